// Round 1
// baseline (114.345 us; speedup 1.0000x reference)
//
#include <hip/hip_runtime.h>

#if defined(__has_builtin)
#if __has_builtin(__builtin_amdgcn_exp2f)
#define EXP2F(x) __builtin_amdgcn_exp2f(x)
#endif
#endif
#ifndef EXP2F
#define EXP2F(x) exp2f(x)
#endif

#define BLOCK 256
#define QPT 4       // queries per thread
#define TILE 512    // train points staged in LDS per iteration
#define MAX_SEGS 32

// scores = -0.5*((q-x)*w)^2 ; fold sqrt(0.5*log2(e)) into w so we can use
// exp2 directly: exp2(-(t*t)) with t = (q-x)*w*K  ==  e^{-0.5*((q-x)w)^2}
#define KFOLD 0.8493218f  // sqrt(0.5 * log2(e))

__global__ __launch_bounds__(BLOCK) void nw_partial(
    const float* __restrict__ q, const float* __restrict__ xt,
    const float* __restrict__ yt, const float* __restrict__ w,
    float2* __restrict__ partial, int n_q, int n_t, int segs)
{
    __shared__ float4 tile[TILE];
    const int seg = blockIdx.x;
    const int tid = threadIdx.x;
    const int qbase = blockIdx.y * (BLOCK * QPT) + tid;

    float qv[QPT], den[QPT], num[QPT];
#pragma unroll
    for (int i = 0; i < QPT; ++i) {
        int qi = qbase + i * BLOCK;
        qv[i] = (qi < n_q) ? q[qi] : 0.f;
        den[i] = 0.f;
        num[i] = 0.f;
    }

    const int seg_len = (n_t + segs - 1) / segs;
    const int s0 = seg * seg_len;
    const int s1 = min(s0 + seg_len, n_t);

    for (int base = s0; base < s1; base += TILE) {
        const int cnt = min(TILE, s1 - base);
        __syncthreads();
        for (int j = tid; j < cnt; j += BLOCK) {
            tile[j] = make_float4(xt[base + j], yt[base + j],
                                  w[base + j] * KFOLD, 0.f);
        }
        __syncthreads();
#pragma unroll 4
        for (int j = 0; j < cnt; ++j) {
            float4 v = tile[j];
#pragma unroll
            for (int i = 0; i < QPT; ++i) {
                float t = (qv[i] - v.x) * v.z;
                float e = EXP2F(-(t * t));
                den[i] += e;
                num[i] = fmaf(e, v.y, num[i]);
            }
        }
    }

#pragma unroll
    for (int i = 0; i < QPT; ++i) {
        int qi = qbase + i * BLOCK;
        if (qi < n_q) partial[seg * n_q + qi] = make_float2(num[i], den[i]);
    }
}

__global__ __launch_bounds__(BLOCK) void nw_reduce(
    const float2* __restrict__ partial, float* __restrict__ out,
    int n_q, int segs)
{
    int qi = blockIdx.x * blockDim.x + threadIdx.x;
    if (qi >= n_q) return;
    float num = 0.f, den = 0.f;
    for (int s = 0; s < segs; ++s) {
        float2 p = partial[s * n_q + qi];
        num += p.x;
        den += p.y;
    }
    out[qi] = num / den;
}

extern "C" void kernel_launch(void* const* d_in, const int* in_sizes, int n_in,
                              void* d_out, int out_size, void* d_ws, size_t ws_size,
                              hipStream_t stream) {
    const float* q  = (const float*)d_in[0];
    const float* xt = (const float*)d_in[1];
    const float* yt = (const float*)d_in[2];
    const float* w  = (const float*)d_in[3];
    const int n_q = in_sizes[0];
    const int n_t = in_sizes[1];

    // split-K segments, clamped so partials fit in the workspace
    int segs = MAX_SEGS;
    size_t need = (size_t)segs * (size_t)n_q * sizeof(float2);
    if (need > ws_size) {
        segs = (int)(ws_size / ((size_t)n_q * sizeof(float2)));
        if (segs < 1) segs = 1;
    }

    float2* partial = (float2*)d_ws;
    dim3 grid(segs, (n_q + BLOCK * QPT - 1) / (BLOCK * QPT));
    nw_partial<<<grid, BLOCK, 0, stream>>>(q, xt, yt, w, partial, n_q, n_t, segs);
    nw_reduce<<<(n_q + BLOCK - 1) / BLOCK, BLOCK, 0, stream>>>(partial,
                                                              (float*)d_out,
                                                              n_q, segs);
}